// Round 1
// baseline (461.091 us; speedup 1.0000x reference)
//
#include <hip/hip_runtime.h>
#include <hip/hip_bf16.h>
#include <stdint.h>
#include <math.h>

// Problem constants
#define BB 4
#define NN 2048
#define DD 1024
#define HH 16
#define HDD 64
#define SS 11

#define D4_0 0.4829629131445341f
#define D4_1 0.8365163037378079f
#define D4_2 0.2241438680420134f
#define D4_3 (-0.1294095225512604f)

typedef __bf16 bf16_t;
typedef __bf16 bf16x4_t __attribute__((ext_vector_type(4)));
typedef __bf16 bf16x8_t __attribute__((ext_vector_type(8)));
typedef float f32x4_t __attribute__((ext_vector_type(4)));

// ---------------- f32 -> bf16 conversion (vectorized) ----------------
__global__ __launch_bounds__(256) void cvt_k(const float* __restrict__ src,
                                             bf16_t* __restrict__ dst, int n4) {
  int i = blockIdx.x * 256 + threadIdx.x;
  if (i >= n4) return;
  f32x4_t v = ((const f32x4_t*)src)[i];
  bf16x4_t o;
  o[0] = (bf16_t)v[0]; o[1] = (bf16_t)v[1]; o[2] = (bf16_t)v[2]; o[3] = (bf16_t)v[3];
  ((bf16x4_t*)dst)[i] = o;
}

// ---------------- async global->LDS helper ----------------
__device__ __forceinline__ void gload16(const void* g, void* l) {
  __builtin_amdgcn_global_load_lds((__attribute__((address_space(1))) void*)(void*)g,
                                   (__attribute__((address_space(3))) void*)l,
                                   16, 0, 0);
}

// ---------------- NT bf16 GEMM: C[M,N] = A[M,K] * Bw[N,K]^T + bias ----------------
// MODE 0: N=4096; cols <3072 -> out0 = qkv (ld 3072); cols >=3072 -> out1 = sigmoid (ld 1024)
// MODE 1: out0[M,N] = val + bias (ld = Nn)
template <int MODE>
__global__ __launch_bounds__(256) void gemm_nt(const bf16_t* __restrict__ A,
                                               const bf16_t* __restrict__ Bw,
                                               const float* __restrict__ bias,
                                               float* __restrict__ out0,
                                               float* __restrict__ out1,
                                               int M, int Nn, int K) {
  __shared__ bf16_t As[128 * 64];
  __shared__ bf16_t Bs[128 * 64];

  const int tid = threadIdx.x;
  const int ntiles = Nn >> 7;
  const int mtile = blockIdx.x / ntiles;
  const int ntile = blockIdx.x % ntiles;
  const int row0 = mtile << 7;
  const int col0 = ntile << 7;
  const int w = tid >> 6, lane = tid & 63;
  const int wm = w >> 1, wn = w & 1;
  const int m16 = lane & 15, quad = lane >> 4;

  f32x4_t acc[4][4];
#pragma unroll
  for (int i = 0; i < 4; i++)
#pragma unroll
    for (int j = 0; j < 4; j++) acc[i][j] = (f32x4_t){0.f, 0.f, 0.f, 0.f};

  for (int kb = 0; kb < K; kb += 64) {
    __syncthreads();  // previous tile's reads done before overwrite
#pragma unroll
    for (int r = 0; r < 4; ++r) {
      int c = r * 256 + tid;       // chunk index (16B units)
      int row = c >> 3, kc = c & 7;
      int swz = kc ^ (row & 7);    // XOR swizzle: LDS chunk kc holds global chunk swz
      const bf16_t* gpA = A + (size_t)(row0 + row) * K + kb + swz * 8;
      const bf16_t* gpB = Bw + (size_t)(col0 + row) * K + kb + swz * 8;
      // wave-uniform LDS base; HW adds lane*16
      bf16_t* lpA = As + (size_t)(r * 256 + (tid & 192)) * 8;
      bf16_t* lpB = Bs + (size_t)(r * 256 + (tid & 192)) * 8;
      gload16(gpA, lpA);
      gload16(gpB, lpB);
    }
    __syncthreads();  // drains vmcnt -> LDS data visible

#pragma unroll
    for (int kk = 0; kk < 2; ++kk) {
      bf16x8_t af[4], bfr[4];
      const int kc = (kk << 2) + quad;
#pragma unroll
      for (int i = 0; i < 4; i++) {
        int arow = (wm << 6) + (i << 4) + m16;
        af[i] = *(const bf16x8_t*)(As + arow * 64 + ((kc ^ (arow & 7)) << 3));
        int brow = (wn << 6) + (i << 4) + m16;
        bfr[i] = *(const bf16x8_t*)(Bs + brow * 64 + ((kc ^ (brow & 7)) << 3));
      }
#pragma unroll
      for (int i = 0; i < 4; i++)
#pragma unroll
        for (int j = 0; j < 4; j++)
          acc[i][j] = __builtin_amdgcn_mfma_f32_16x16x32_bf16(af[i], bfr[j], acc[i][j], 0, 0, 0);
    }
  }

  // epilogue: C[row = quad*4+r][col = lane&15]
#pragma unroll
  for (int i = 0; i < 4; i++) {
#pragma unroll
    for (int j = 0; j < 4; j++) {
      const int grow0 = row0 + (wm << 6) + (i << 4) + (quad << 2);
      const int gcol = col0 + (wn << 6) + (j << 4) + m16;
      const float bval = bias[gcol];
#pragma unroll
      for (int r = 0; r < 4; r++) {
        float val = acc[i][j][r] + bval;
        if (MODE == 0) {
          if (gcol < 3072)
            out0[(size_t)(grow0 + r) * 3072 + gcol] = val;
          else
            out1[(size_t)(grow0 + r) * 1024 + (gcol - 3072)] = 1.f / (1.f + __expf(-val));
        } else {
          out0[(size_t)(grow0 + r) * Nn + gcol] = val;
        }
      }
    }
  }
}

// ---------------- field + gains: one wave per (b,n,h) ----------------
__global__ __launch_bounds__(256) void field_gains_k(const float* __restrict__ qkv,
                                                     const float* __restrict__ scale_gain,
                                                     const float* __restrict__ Wqs,
                                                     float* __restrict__ field,
                                                     float* __restrict__ gains) {
  const int tid = threadIdx.x;
  const int w = tid >> 6, lane = tid & 63;
  const int task = blockIdx.x * 4 + w;  // task = bn*16 + h
  const int h = task & 15;
  const int bn = task >> 4;             // b*2048 + n
  const float* qp = qkv + (size_t)bn * 3072;
  const float q = qp[h * 64 + lane];
  const float k = qp[1024 + h * 64 + lane];
  const float v = qp[2048 + h * 64 + lane];

  float ksq = k * k;
#pragma unroll
  for (int s = 32; s; s >>= 1) ksq += __shfl_xor(ksq, s, 64);
  const float kmag = sqrtf(ksq);

  const int b = bn >> 11, n = bn & 2047;
  const size_t bh = (size_t)(b * 16 + h);
  field[(bh * 2048 + n) * 64 + lane] = v * kmag;

  float logit[SS];
#pragma unroll
  for (int s = 0; s < SS; s++) {
    float p = q * Wqs[s * 64 + lane];
#pragma unroll
    for (int sh = 32; sh; sh >>= 1) p += __shfl_xor(p, sh, 64);
    logit[s] = p + scale_gain[s * 16 + h];
  }
  float mx = logit[0];
#pragma unroll
  for (int s = 1; s < SS; s++) mx = fmaxf(mx, logit[s]);
  float e[SS];
  float se = 0.f;
#pragma unroll
  for (int s = 0; s < SS; s++) { e[s] = __expf(logit[s] - mx); se += e[s]; }
  const float inv = 1.f / se;
  float gv = 0.f;
#pragma unroll
  for (int s = 0; s < SS; s++)
    if (lane == s) gv = e[s] * inv;
  if (lane < SS) gains[(bh * 2048 + n) * SS + lane] = gv;
}

// ---------------- multiscale causal D4 conv, offset-collapsed ----------------
__global__ __launch_bounds__(256) void conv_k(const float* __restrict__ field,
                                              const float* __restrict__ gains,
                                              float* __restrict__ facc) {
  const int tid = threadIdx.x;
  const int hd = tid & 63;
  const int nsub = tid >> 6;
  const int blk = blockIdx.x;          // (b*16+h)*512 + ntile
  const int ntile = blk & 511;
  const int bh = blk >> 9;
  const int n = ntile * 4 + nsub;
  const float* frow = field + (size_t)bh * 2048 * 64;
  const float* gp = gains + ((size_t)bh * 2048 + n) * SS;

  float g[SS];
#pragma unroll
  for (int s = 0; s < SS; s++) g[s] = gp[s];

  float acc = D4_3 * frow[(size_t)n * 64 + hd];  // offset 0: sum_s g_s = 1
#pragma unroll
  for (int j = 0; j < 11; j++) {                 // offsets 2^j (j=11 unreachable, n<2048)
    float wgt = D4_2 * g[j];
    if (j >= 1) wgt += D4_1 * g[j - 1];
    int off = 1 << j;
    if (n >= off) acc += wgt * frow[(size_t)(n - off) * 64 + hd];
  }
#pragma unroll
  for (int j = 0; j < 10; j++) {                 // offsets 3*2^j (j=10 unreachable)
    int off = 3 << j;
    if (n >= off) acc += (D4_0 * g[j]) * frow[(size_t)(n - off) * 64 + hd];
  }
  facc[((size_t)bh * 2048 + n) * 64 + hd] = acc;
}

// ---------------- head coupling softmax mix + gate + bf16 cast ----------------
__global__ __launch_bounds__(1024) void couple_gate_k(const float* __restrict__ facc,
                                                      const float* __restrict__ fcoup,
                                                      const float* __restrict__ gate,
                                                      bf16_t* __restrict__ gmat) {
  __shared__ float sacc[1024];
  __shared__ float sc[256];
  __shared__ float scn[256];
  const int tid = threadIdx.x;
  const int bn = blockIdx.x;  // b*2048 + n
  const int b = bn >> 11, n = bn & 2047;
  if (tid < 256) sc[tid] = fcoup[tid];
  const int i = tid >> 6, hd = tid & 63;
  sacc[tid] = facc[(((size_t)(b * 16 + i)) * 2048 + n) * 64 + hd];
  __syncthreads();
  if (tid < 16) {
    float row[16];
    float mx = -1e30f;
#pragma unroll
    for (int j = 0; j < 16; j++) { row[j] = sc[tid * 16 + j]; mx = fmaxf(mx, row[j]); }
    float se = 0.f;
#pragma unroll
    for (int j = 0; j < 16; j++) { row[j] = __expf(row[j] - mx); se += row[j]; }
    float inv = 1.f / se;
#pragma unroll
    for (int j = 0; j < 16; j++) scn[tid * 16 + j] = row[j] * inv;
  }
  __syncthreads();
  float s = 0.f;
#pragma unroll
  for (int j = 0; j < 16; j++) s += scn[i * 16 + j] * sacc[j * 64 + hd];
  const float gt = gate[(size_t)bn * 1024 + tid];
  gmat[(size_t)bn * 1024 + tid] = (bf16_t)(s * gt);
}

// ---------------- launch ----------------
extern "C" void kernel_launch(void* const* d_in, const int* in_sizes, int n_in,
                              void* d_out, int out_size, void* d_ws, size_t ws_size,
                              hipStream_t stream) {
  (void)in_sizes; (void)n_in; (void)out_size; (void)ws_size;
  const float* x = (const float*)d_in[0];
  const float* Wqkv = (const float*)d_in[1];
  const float* bqkv = (const float*)d_in[2];
  const float* Wo = (const float*)d_in[3];
  const float* bo = (const float*)d_in[4];
  const float* Wg = (const float*)d_in[5];
  const float* bg = (const float*)d_in[6];
  const float* scale_gain = (const float*)d_in[7];
  const float* Wqs = (const float*)d_in[8];
  const float* fcoup = (const float*)d_in[9];

  char* ws = (char*)d_ws;
  size_t off = 0;
  auto alloc = [&](size_t bytes) {
    void* p = ws + off;
    off += (bytes + 255) & ~(size_t)255;
    return p;
  };
  bf16_t* xb = (bf16_t*)alloc(8192ull * 1024 * 2);      // 16 MB
  bf16_t* Wab = (bf16_t*)alloc(4096ull * 1024 * 2);     // 8 MB (Wqkv rows then Wg rows)
  bf16_t* Wob = (bf16_t*)alloc(1024ull * 1024 * 2);     // 2 MB
  float* biasA = (float*)alloc(4096ull * 4);
  float* qkv = (float*)alloc(8192ull * 3072 * 4);       // 96 MB (reused below)
  float* gate = (float*)alloc(8192ull * 1024 * 4);      // 32 MB
  float* field = (float*)alloc(33554432ull);            // 32 MB
  float* gains = (float*)alloc(5767168ull);             // 5.5 MB
  // reuse qkv region after field/gains computed:
  float* facc = qkv;                                    // 32 MB
  bf16_t* gmat = (bf16_t*)((char*)qkv + 8192ull * 1024 * 4);  // +32MB, 16 MB

  // bias concat for fused GEMM-A
  hipMemcpyAsync(biasA, bqkv, 3072 * 4, hipMemcpyDeviceToDevice, stream);
  hipMemcpyAsync(biasA + 3072, bg, 1024 * 4, hipMemcpyDeviceToDevice, stream);

  // conversions
  cvt_k<<<8192, 256, 0, stream>>>(x, xb, 8192 * 1024 / 4);
  cvt_k<<<3072, 256, 0, stream>>>(Wqkv, Wab, 3072 * 1024 / 4);
  cvt_k<<<1024, 256, 0, stream>>>(Wg, Wab + 3072ull * 1024, 1024 * 1024 / 4);
  cvt_k<<<1024, 256, 0, stream>>>(Wo, Wob, 1024 * 1024 / 4);

  // GEMM-A: qkv + gate fused (M=8192, N=4096, K=1024)
  gemm_nt<0><<<64 * 32, 256, 0, stream>>>(xb, Wab, biasA, qkv, gate, 8192, 4096, 1024);

  // field + gains
  field_gains_k<<<32768, 256, 0, stream>>>(qkv, scale_gain, Wqs, field, gains);

  // multiscale conv
  conv_k<<<32768, 256, 0, stream>>>(field, gains, facc);

  // coupling + gate + bf16 cast
  couple_gate_k<<<8192, 1024, 0, stream>>>(facc, fcoup, gate, gmat);

  // GEMM-B: output (M=8192, N=1024, K=1024)
  gemm_nt<1><<<64 * 8, 256, 0, stream>>>(gmat, Wob, bo, (float*)d_out, nullptr, 8192, 1024, 1024);
}

// Round 2
// 388.235 us; speedup vs baseline: 1.1877x; 1.1877x over previous
//
#include <hip/hip_runtime.h>
#include <hip/hip_bf16.h>
#include <stdint.h>
#include <math.h>

// Problem constants
#define BB 4
#define NN 2048
#define DD 1024
#define HH 16
#define HDD 64
#define SS 11

#define D4_0 0.4829629131445341f
#define D4_1 0.8365163037378079f
#define D4_2 0.2241438680420134f
#define D4_3 (-0.1294095225512604f)

typedef __bf16 bf16_t;
typedef __bf16 bf16x4_t __attribute__((ext_vector_type(4)));
typedef __bf16 bf16x8_t __attribute__((ext_vector_type(8)));
typedef float f32x4_t __attribute__((ext_vector_type(4)));

// ---------------- f32 -> bf16 conversion (vectorized) ----------------
__global__ __launch_bounds__(256) void cvt_k(const float* __restrict__ src,
                                             bf16_t* __restrict__ dst, int n4) {
  int i = blockIdx.x * 256 + threadIdx.x;
  if (i >= n4) return;
  f32x4_t v = ((const f32x4_t*)src)[i];
  bf16x4_t o;
  o[0] = (bf16_t)v[0]; o[1] = (bf16_t)v[1]; o[2] = (bf16_t)v[2]; o[3] = (bf16_t)v[3];
  ((bf16x4_t*)dst)[i] = o;
}

// ---------------- async global->LDS helper ----------------
__device__ __forceinline__ void gload16(const void* g, void* l) {
  __builtin_amdgcn_global_load_lds((__attribute__((address_space(1))) void*)(void*)g,
                                   (__attribute__((address_space(3))) void*)l,
                                   16, 0, 0);
}

// ---------------- NT bf16 GEMM: C[M,N] = A[M,K] * Bw[N,K]^T + bias ----------------
// MODE 0: N=4096; cols <3072 -> out0 = qkv bf16 (ld 3072); cols >=3072 -> out1 = sigmoid bf16 (ld 1024)
// MODE 1: out0[M,N] = fp32 val + bias (ld = Nn)
template <int MODE>
__global__ __launch_bounds__(256) void gemm_nt(const bf16_t* __restrict__ A,
                                               const bf16_t* __restrict__ Bw,
                                               const float* __restrict__ bias,
                                               void* __restrict__ out0v,
                                               void* __restrict__ out1v,
                                               int M, int Nn, int K) {
  __shared__ bf16_t As[128 * 64];
  __shared__ bf16_t Bs[128 * 64];

  const int tid = threadIdx.x;
  const int ntiles = Nn >> 7;
  const int mtile = blockIdx.x / ntiles;
  const int ntile = blockIdx.x % ntiles;
  const int row0 = mtile << 7;
  const int col0 = ntile << 7;
  const int w = tid >> 6, lane = tid & 63;
  const int wm = w >> 1, wn = w & 1;
  const int m16 = lane & 15, quad = lane >> 4;

  f32x4_t acc[4][4];
#pragma unroll
  for (int i = 0; i < 4; i++)
#pragma unroll
    for (int j = 0; j < 4; j++) acc[i][j] = (f32x4_t){0.f, 0.f, 0.f, 0.f};

  for (int kb = 0; kb < K; kb += 64) {
    __syncthreads();  // previous tile's reads done before overwrite
#pragma unroll
    for (int r = 0; r < 4; ++r) {
      int c = r * 256 + tid;       // chunk index (16B units)
      int row = c >> 3, kc = c & 7;
      int swz = kc ^ (row & 7);    // XOR swizzle: LDS chunk kc holds global chunk swz
      const bf16_t* gpA = A + (size_t)(row0 + row) * K + kb + swz * 8;
      const bf16_t* gpB = Bw + (size_t)(col0 + row) * K + kb + swz * 8;
      // wave-uniform LDS base; HW adds lane*16
      bf16_t* lpA = As + (size_t)(r * 256 + (tid & 192)) * 8;
      bf16_t* lpB = Bs + (size_t)(r * 256 + (tid & 192)) * 8;
      gload16(gpA, lpA);
      gload16(gpB, lpB);
    }
    __syncthreads();  // drains vmcnt -> LDS data visible

#pragma unroll
    for (int kk = 0; kk < 2; ++kk) {
      bf16x8_t af[4], bfr[4];
      const int kc = (kk << 2) + quad;
#pragma unroll
      for (int i = 0; i < 4; i++) {
        int arow = (wm << 6) + (i << 4) + m16;
        af[i] = *(const bf16x8_t*)(As + arow * 64 + ((kc ^ (arow & 7)) << 3));
        int brow = (wn << 6) + (i << 4) + m16;
        bfr[i] = *(const bf16x8_t*)(Bs + brow * 64 + ((kc ^ (brow & 7)) << 3));
      }
#pragma unroll
      for (int i = 0; i < 4; i++)
#pragma unroll
        for (int j = 0; j < 4; j++)
          acc[i][j] = __builtin_amdgcn_mfma_f32_16x16x32_bf16(af[i], bfr[j], acc[i][j], 0, 0, 0);
    }
  }

  // epilogue: C[row = quad*4+r][col = lane&15]
#pragma unroll
  for (int i = 0; i < 4; i++) {
#pragma unroll
    for (int j = 0; j < 4; j++) {
      const int grow0 = row0 + (wm << 6) + (i << 4) + (quad << 2);
      const int gcol = col0 + (wn << 6) + (j << 4) + m16;
      const float bval = bias[gcol];
#pragma unroll
      for (int r = 0; r < 4; r++) {
        float val = acc[i][j][r] + bval;
        if (MODE == 0) {
          if (gcol < 3072)
            ((bf16_t*)out0v)[(size_t)(grow0 + r) * 3072 + gcol] = (bf16_t)val;
          else
            ((bf16_t*)out1v)[(size_t)(grow0 + r) * 1024 + (gcol - 3072)] =
                (bf16_t)(1.f / (1.f + __expf(-val)));
        } else {
          ((float*)out0v)[(size_t)(grow0 + r) * Nn + gcol] = val;
        }
      }
    }
  }
}

// ---------------- field + gains via MFMA: one wave per bn (16 heads) ----------------
// qkvb: [8192][3072] bf16.  logits = q(16x64) . Wqs(11x64)^T via 2 MFMAs;
// ksq = diag(K . K^T) via 2 MFMAs; softmax over s = 4-step shfl within quad group.
__global__ __launch_bounds__(256) void field_gains_k(const bf16_t* __restrict__ qkvb,
                                                     const float* __restrict__ scale_gain,
                                                     const float* __restrict__ Wqs,
                                                     bf16_t* __restrict__ fieldb,
                                                     float* __restrict__ gains) {
  __shared__ float skmag[4 * 16];
  const int tid = threadIdx.x;
  const int w = tid >> 6, lane = tid & 63;
  const int bn = blockIdx.x * 4 + w;  // 0..8191
  const int b = bn >> 11, n_pos = bn & 2047;
  const int m16 = lane & 15, quad = lane >> 4;
  const bf16_t* qp = qkvb + (size_t)bn * 3072;

  // A-fragments: q rows (head = m16), k rows
  bf16x8_t aq[2], ak[2], bw[2];
#pragma unroll
  for (int it = 0; it < 2; it++) {
    const int koff = it * 32 + quad * 8;
    aq[it] = *(const bf16x8_t*)(qp + m16 * 64 + koff);
    ak[it] = *(const bf16x8_t*)(qp + 1024 + m16 * 64 + koff);
    // B-fragment: Wqs rows (s = m16), fp32 -> bf16, zero-pad s>=11
    bf16x8_t bwv;
    if (m16 < SS) {
      const float* wp = Wqs + m16 * 64 + koff;
#pragma unroll
      for (int j = 0; j < 8; j++) bwv[j] = (bf16_t)wp[j];
    } else {
#pragma unroll
      for (int j = 0; j < 8; j++) bwv[j] = (bf16_t)0.f;
    }
    bw[it] = bwv;
  }

  f32x4_t acc_l = (f32x4_t){0.f, 0.f, 0.f, 0.f};
  f32x4_t acc_k = (f32x4_t){0.f, 0.f, 0.f, 0.f};
#pragma unroll
  for (int it = 0; it < 2; it++) {
    acc_l = __builtin_amdgcn_mfma_f32_16x16x32_bf16(aq[it], bw[it], acc_l, 0, 0, 0);
    acc_k = __builtin_amdgcn_mfma_f32_16x16x32_bf16(ak[it], ak[it], acc_k, 0, 0, 0);
  }

  // ksq diag extraction: D[m][n], m=quad*4+r, n=m16; diag where m16==m
#pragma unroll
  for (int r = 0; r < 4; r++) {
    if (m16 == quad * 4 + r) skmag[w * 16 + m16] = sqrtf(fmaxf(acc_k[r], 0.f));
  }

  // softmax over s (cols n=m16, valid n<11) for each head row m=quad*4+r
#pragma unroll
  for (int r = 0; r < 4; r++) {
    const int m = quad * 4 + r;
    float lg = (m16 < SS) ? (acc_l[r] + scale_gain[m16 * 16 + m]) : -1e30f;
    float mx = lg;
#pragma unroll
    for (int sh = 1; sh < 16; sh <<= 1) mx = fmaxf(mx, __shfl_xor(mx, sh, 64));
    float e = (m16 < SS) ? __expf(lg - mx) : 0.f;
    float se = e;
#pragma unroll
    for (int sh = 1; sh < 16; sh <<= 1) se += __shfl_xor(se, sh, 64);
    if (m16 < SS)
      gains[((size_t)(b * 16 + m) * 2048 + n_pos) * SS + m16] = e / se;
  }

  __syncthreads();

  // field[bh][n][hd] = v[h][hd] * kmag[h], bf16 out, lane = hd
#pragma unroll
  for (int h = 0; h < 16; h++) {
    const float km = skmag[w * 16 + h];
    const float v = (float)qp[2048 + h * 64 + lane];
    fieldb[((size_t)(b * 16 + h) * 2048 + n_pos) * 64 + lane] = (bf16_t)(v * km);
  }
}

// ---------------- multiscale causal D4 conv, offset-collapsed ----------------
__global__ __launch_bounds__(256) void conv_k(const bf16_t* __restrict__ field,
                                              const float* __restrict__ gains,
                                              float* __restrict__ facc) {
  const int tid = threadIdx.x;
  const int hd = tid & 63;
  const int nsub = tid >> 6;
  const int blk = blockIdx.x;          // (b*16+h)*512 + ntile
  const int ntile = blk & 511;
  const int bh = blk >> 9;
  const int n = ntile * 4 + nsub;
  const bf16_t* frow = field + (size_t)bh * 2048 * 64;
  const float* gp = gains + ((size_t)bh * 2048 + n) * SS;

  float g[SS];
#pragma unroll
  for (int s = 0; s < SS; s++) g[s] = gp[s];

  float acc = D4_3 * (float)frow[(size_t)n * 64 + hd];  // offset 0: sum_s g_s = 1
#pragma unroll
  for (int j = 0; j < 11; j++) {                 // offsets 2^j
    float wgt = D4_2 * g[j];
    if (j >= 1) wgt += D4_1 * g[j - 1];
    int off = 1 << j;
    if (n >= off) acc += wgt * (float)frow[(size_t)(n - off) * 64 + hd];
  }
#pragma unroll
  for (int j = 0; j < 10; j++) {                 // offsets 3*2^j
    int off = 3 << j;
    if (n >= off) acc += (D4_0 * g[j]) * (float)frow[(size_t)(n - off) * 64 + hd];
  }
  facc[((size_t)bh * 2048 + n) * 64 + hd] = acc;
}

// ---------------- head coupling softmax mix + gate + bf16 cast ----------------
__global__ __launch_bounds__(1024) void couple_gate_k(const float* __restrict__ facc,
                                                      const float* __restrict__ fcoup,
                                                      const bf16_t* __restrict__ gate,
                                                      bf16_t* __restrict__ gmat) {
  __shared__ float sacc[1024];
  __shared__ float sc[256];
  __shared__ float scn[256];
  const int tid = threadIdx.x;
  const int bn = blockIdx.x;  // b*2048 + n
  const int b = bn >> 11, n = bn & 2047;
  if (tid < 256) sc[tid] = fcoup[tid];
  const int i = tid >> 6, hd = tid & 63;
  sacc[tid] = facc[(((size_t)(b * 16 + i)) * 2048 + n) * 64 + hd];
  __syncthreads();
  if (tid < 16) {
    float row[16];
    float mx = -1e30f;
#pragma unroll
    for (int j = 0; j < 16; j++) { row[j] = sc[tid * 16 + j]; mx = fmaxf(mx, row[j]); }
    float se = 0.f;
#pragma unroll
    for (int j = 0; j < 16; j++) { row[j] = __expf(row[j] - mx); se += row[j]; }
    float inv = 1.f / se;
#pragma unroll
    for (int j = 0; j < 16; j++) scn[tid * 16 + j] = row[j] * inv;
  }
  __syncthreads();
  float s = 0.f;
#pragma unroll
  for (int j = 0; j < 16; j++) s += scn[i * 16 + j] * sacc[j * 64 + hd];
  const float gt = (float)gate[(size_t)bn * 1024 + tid];
  gmat[(size_t)bn * 1024 + tid] = (bf16_t)(s * gt);
}

// ---------------- launch ----------------
extern "C" void kernel_launch(void* const* d_in, const int* in_sizes, int n_in,
                              void* d_out, int out_size, void* d_ws, size_t ws_size,
                              hipStream_t stream) {
  (void)in_sizes; (void)n_in; (void)out_size; (void)ws_size;
  const float* x = (const float*)d_in[0];
  const float* Wqkv = (const float*)d_in[1];
  const float* bqkv = (const float*)d_in[2];
  const float* Wo = (const float*)d_in[3];
  const float* bo = (const float*)d_in[4];
  const float* Wg = (const float*)d_in[5];
  const float* bg = (const float*)d_in[6];
  const float* scale_gain = (const float*)d_in[7];
  const float* Wqs = (const float*)d_in[8];
  const float* fcoup = (const float*)d_in[9];

  char* ws = (char*)d_ws;
  size_t off = 0;
  auto alloc = [&](size_t bytes) {
    void* p = ws + off;
    off += (bytes + 255) & ~(size_t)255;
    return p;
  };
  bf16_t* xb = (bf16_t*)alloc(8192ull * 1024 * 2);      // 16 MB
  bf16_t* Wab = (bf16_t*)alloc(4096ull * 1024 * 2);     // 8 MB (Wqkv rows then Wg rows)
  bf16_t* Wob = (bf16_t*)alloc(1024ull * 1024 * 2);     // 2 MB
  float* biasA = (float*)alloc(4096ull * 4);
  bf16_t* qkvb = (bf16_t*)alloc(8192ull * 3072 * 2);    // 48 MB
  bf16_t* gateb = (bf16_t*)alloc(8192ull * 1024 * 2);   // 16 MB
  bf16_t* fieldb = (bf16_t*)alloc(8388608ull * 2);      // 16 MB
  float* gains = (float*)alloc(8192ull * 16 * SS * 4);  // 5.8 MB
  float* facc = (float*)alloc(8388608ull * 4);          // 32 MB
  bf16_t* gmat = (bf16_t*)alloc(8192ull * 1024 * 2);    // 16 MB

  // bias concat for fused GEMM-A
  hipMemcpyAsync(biasA, bqkv, 3072 * 4, hipMemcpyDeviceToDevice, stream);
  hipMemcpyAsync(biasA + 3072, bg, 1024 * 4, hipMemcpyDeviceToDevice, stream);

  // conversions
  cvt_k<<<8192, 256, 0, stream>>>(x, xb, 8192 * 1024 / 4);
  cvt_k<<<3072, 256, 0, stream>>>(Wqkv, Wab, 3072 * 1024 / 4);
  cvt_k<<<1024, 256, 0, stream>>>(Wg, Wab + 3072ull * 1024, 1024 * 1024 / 4);
  cvt_k<<<1024, 256, 0, stream>>>(Wo, Wob, 1024 * 1024 / 4);

  // GEMM-A: qkv + gate fused (M=8192, N=4096, K=1024), bf16 outputs
  gemm_nt<0><<<64 * 32, 256, 0, stream>>>(xb, Wab, biasA, qkvb, gateb, 8192, 4096, 1024);

  // field + gains (MFMA-based, one wave per bn)
  field_gains_k<<<2048, 256, 0, stream>>>(qkvb, scale_gain, Wqs, fieldb, gains);

  // multiscale conv
  conv_k<<<32768, 256, 0, stream>>>(fieldb, gains, facc);

  // coupling + gate + bf16 cast
  couple_gate_k<<<8192, 1024, 0, stream>>>(facc, fcoup, gateb, gmat);

  // GEMM-B: output (M=8192, N=1024, K=1024), fp32 out
  gemm_nt<1><<<64 * 8, 256, 0, stream>>>(gmat, Wob, bo, (void*)d_out, nullptr, 8192, 1024, 1024);
}

// Round 4
// 290.528 us; speedup vs baseline: 1.5871x; 1.3363x over previous
//
#include <hip/hip_runtime.h>
#include <hip/hip_bf16.h>
#include <stdint.h>
#include <math.h>

// Problem constants
#define BB 4
#define NN 2048
#define DD 1024
#define HH 16
#define HDD 64
#define SS 11

#define D4_0 0.4829629131445341f
#define D4_1 0.8365163037378079f
#define D4_2 0.2241438680420134f
#define D4_3 (-0.1294095225512604f)

typedef __bf16 bf16_t;
typedef __bf16 bf16x4_t __attribute__((ext_vector_type(4)));
typedef __bf16 bf16x8_t __attribute__((ext_vector_type(8)));
typedef float f32x4_t __attribute__((ext_vector_type(4)));

// ---------------- f32 -> bf16 conversion (vectorized) ----------------
__global__ __launch_bounds__(256) void cvt_k(const float* __restrict__ src,
                                             bf16_t* __restrict__ dst, int n4) {
  int i = blockIdx.x * 256 + threadIdx.x;
  if (i >= n4) return;
  f32x4_t v = ((const f32x4_t*)src)[i];
  bf16x4_t o;
  o[0] = (bf16_t)v[0]; o[1] = (bf16_t)v[1]; o[2] = (bf16_t)v[2]; o[3] = (bf16_t)v[3];
  ((bf16x4_t*)dst)[i] = o;
}

// ---------------- async global->LDS helper ----------------
__device__ __forceinline__ void gload16(const void* g, void* l) {
  __builtin_amdgcn_global_load_lds((__attribute__((address_space(1))) void*)(void*)g,
                                   (__attribute__((address_space(3))) void*)l,
                                   16, 0, 0);
}

// ---------------- NT bf16 GEMM: C[M,N] = A[M,K] * Bw[N,K]^T + bias ----------------
// MODE 0: N=4096; cols <3072 -> out0 = qkv bf16 (ld 3072); cols >=3072 -> out1 = sigmoid bf16 (ld 1024)
// MODE 1: out0[M,N] = fp32 val + bias (ld = Nn)
template <int MODE>
__global__ __launch_bounds__(256) void gemm_nt(const bf16_t* __restrict__ A,
                                               const bf16_t* __restrict__ Bw,
                                               const float* __restrict__ bias,
                                               void* __restrict__ out0v,
                                               void* __restrict__ out1v,
                                               int M, int Nn, int K) {
  __shared__ bf16_t As[128 * 64];
  __shared__ bf16_t Bs[128 * 64];

  const int tid = threadIdx.x;
  const int ntiles = Nn >> 7;
  const int mtile = blockIdx.x / ntiles;
  const int ntile = blockIdx.x % ntiles;
  const int row0 = mtile << 7;
  const int col0 = ntile << 7;
  const int w = tid >> 6, lane = tid & 63;
  const int wm = w >> 1, wn = w & 1;
  const int m16 = lane & 15, quad = lane >> 4;

  f32x4_t acc[4][4];
#pragma unroll
  for (int i = 0; i < 4; i++)
#pragma unroll
    for (int j = 0; j < 4; j++) acc[i][j] = (f32x4_t){0.f, 0.f, 0.f, 0.f};

  for (int kb = 0; kb < K; kb += 64) {
    __syncthreads();  // previous tile's reads done before overwrite
#pragma unroll
    for (int r = 0; r < 4; ++r) {
      int c = r * 256 + tid;       // chunk index (16B units)
      int row = c >> 3, kc = c & 7;
      int swz = kc ^ (row & 7);    // XOR swizzle: LDS chunk kc holds global chunk swz
      const bf16_t* gpA = A + (size_t)(row0 + row) * K + kb + swz * 8;
      const bf16_t* gpB = Bw + (size_t)(col0 + row) * K + kb + swz * 8;
      // wave-uniform LDS base; HW adds lane*16
      bf16_t* lpA = As + (size_t)(r * 256 + (tid & 192)) * 8;
      bf16_t* lpB = Bs + (size_t)(r * 256 + (tid & 192)) * 8;
      gload16(gpA, lpA);
      gload16(gpB, lpB);
    }
    __syncthreads();  // drains vmcnt -> LDS data visible

#pragma unroll
    for (int kk = 0; kk < 2; ++kk) {
      bf16x8_t af[4], bfr[4];
      const int kc = (kk << 2) + quad;
#pragma unroll
      for (int i = 0; i < 4; i++) {
        int arow = (wm << 6) + (i << 4) + m16;
        af[i] = *(const bf16x8_t*)(As + arow * 64 + ((kc ^ (arow & 7)) << 3));
        int brow = (wn << 6) + (i << 4) + m16;
        bfr[i] = *(const bf16x8_t*)(Bs + brow * 64 + ((kc ^ (brow & 7)) << 3));
      }
#pragma unroll
      for (int i = 0; i < 4; i++)
#pragma unroll
        for (int j = 0; j < 4; j++)
          acc[i][j] = __builtin_amdgcn_mfma_f32_16x16x32_bf16(af[i], bfr[j], acc[i][j], 0, 0, 0);
    }
  }

  // epilogue: C[row = quad*4+r][col = lane&15]
#pragma unroll
  for (int i = 0; i < 4; i++) {
#pragma unroll
    for (int j = 0; j < 4; j++) {
      const int grow0 = row0 + (wm << 6) + (i << 4) + (quad << 2);
      const int gcol = col0 + (wn << 6) + (j << 4) + m16;
      const float bval = bias[gcol];
#pragma unroll
      for (int r = 0; r < 4; r++) {
        float val = acc[i][j][r] + bval;
        if (MODE == 0) {
          if (gcol < 3072)
            ((bf16_t*)out0v)[(size_t)(grow0 + r) * 3072 + gcol] = (bf16_t)val;
          else
            ((bf16_t*)out1v)[(size_t)(grow0 + r) * 1024 + (gcol - 3072)] =
                (bf16_t)(1.f / (1.f + __expf(-val)));
        } else {
          ((float*)out0v)[(size_t)(grow0 + r) * Nn + gcol] = val;
        }
      }
    }
  }
}

// ---------------- field + gains via MFMA: one wave per bn (16 heads) ----------------
__global__ __launch_bounds__(256) void field_gains_k(const bf16_t* __restrict__ qkvb,
                                                     const float* __restrict__ scale_gain,
                                                     const float* __restrict__ Wqs,
                                                     bf16_t* __restrict__ fieldb,
                                                     float* __restrict__ gains) {
  __shared__ float skmag[4 * 16];
  const int tid = threadIdx.x;
  const int w = tid >> 6, lane = tid & 63;
  const int bn = blockIdx.x * 4 + w;  // 0..8191
  const int b = bn >> 11, n_pos = bn & 2047;
  const int m16 = lane & 15, quad = lane >> 4;
  const bf16_t* qp = qkvb + (size_t)bn * 3072;

  // A-fragments: q rows (head = m16), k rows
  bf16x8_t aq[2], ak[2], bw[2];
#pragma unroll
  for (int it = 0; it < 2; it++) {
    const int koff = it * 32 + quad * 8;
    aq[it] = *(const bf16x8_t*)(qp + m16 * 64 + koff);
    ak[it] = *(const bf16x8_t*)(qp + 1024 + m16 * 64 + koff);
    bf16x8_t bwv;
    if (m16 < SS) {
      const float* wp = Wqs + m16 * 64 + koff;
#pragma unroll
      for (int j = 0; j < 8; j++) bwv[j] = (bf16_t)wp[j];
    } else {
#pragma unroll
      for (int j = 0; j < 8; j++) bwv[j] = (bf16_t)0.f;
    }
    bw[it] = bwv;
  }

  f32x4_t acc_l = (f32x4_t){0.f, 0.f, 0.f, 0.f};
  f32x4_t acc_k = (f32x4_t){0.f, 0.f, 0.f, 0.f};
#pragma unroll
  for (int it = 0; it < 2; it++) {
    acc_l = __builtin_amdgcn_mfma_f32_16x16x32_bf16(aq[it], bw[it], acc_l, 0, 0, 0);
    acc_k = __builtin_amdgcn_mfma_f32_16x16x32_bf16(ak[it], ak[it], acc_k, 0, 0, 0);
  }

  // ksq diag extraction: D[m][n], m=quad*4+r, n=m16; diag where m16==m
#pragma unroll
  for (int r = 0; r < 4; r++) {
    if (m16 == quad * 4 + r) skmag[w * 16 + m16] = sqrtf(fmaxf(acc_k[r], 0.f));
  }

  // softmax over s (cols n=m16, valid n<11) for each head row m=quad*4+r
#pragma unroll
  for (int r = 0; r < 4; r++) {
    const int m = quad * 4 + r;
    float lg = (m16 < SS) ? (acc_l[r] + scale_gain[m16 * 16 + m]) : -1e30f;
    float mx = lg;
#pragma unroll
    for (int sh = 1; sh < 16; sh <<= 1) mx = fmaxf(mx, __shfl_xor(mx, sh, 64));
    float e = (m16 < SS) ? __expf(lg - mx) : 0.f;
    float se = e;
#pragma unroll
    for (int sh = 1; sh < 16; sh <<= 1) se += __shfl_xor(se, sh, 64);
    if (m16 < SS)
      gains[((size_t)(b * 16 + m) * 2048 + n_pos) * SS + m16] = e / se;
  }

  __syncthreads();

  // field[bh][n][hd] = v[h][hd] * kmag[h], bf16 out, lane = hd
#pragma unroll
  for (int h = 0; h < 16; h++) {
    const float km = skmag[w * 16 + h];
    const float v = (float)qp[2048 + h * 64 + lane];
    fieldb[((size_t)(b * 16 + h) * 2048 + n_pos) * 64 + lane] = (bf16_t)(v * km);
  }
}

// ---------------- multiscale causal D4 conv, offset-collapsed ----------------
// One wave: 8 n-positions x 64 hd (lane = nsub*8 + c, bf16x8 per lane).
// Block: 4 waves = 32 n. blockIdx low 6 bits = bh -> all tiles of a bh on XCD bh%8.
__global__ __launch_bounds__(256) void conv_k(const bf16_t* __restrict__ field,
                                              const float* __restrict__ gains,
                                              bf16_t* __restrict__ facc) {
  __shared__ float sg[32 * SS];
  const int tid = threadIdx.x;
  const int blk = blockIdx.x;
  const int bh = blk & 63;
  const int ntile = blk >> 6;          // 0..63
  const int n0 = ntile * 32;

  // 352 floats with 256 threads: strided fill (R3 bug: single-shot left 96 uninit)
  for (int i = tid; i < 32 * SS; i += 256)
    sg[i] = gains[((size_t)bh * 2048 + n0) * SS + i];
  __syncthreads();

  const int w = tid >> 6, lane = tid & 63;
  const int nsub = lane >> 3, c = lane & 7;
  const int ln = w * 8 + nsub;         // 0..31
  const int n = n0 + ln;
  const bf16_t* frow = field + (size_t)bh * 2048 * 64;

  float g[SS];
#pragma unroll
  for (int s = 0; s < SS; s++) g[s] = sg[ln * SS + s];

  float acc[8];
  {
    bf16x8_t f0 = *(const bf16x8_t*)(frow + (size_t)n * 64 + c * 8);
#pragma unroll
    for (int q = 0; q < 8; q++) acc[q] = D4_3 * (float)f0[q];  // offset 0: sum_s g_s = 1
  }
#pragma unroll
  for (int j = 0; j < 11; j++) {       // offsets 2^j
    float wgt = D4_2 * g[j];
    if (j >= 1) wgt += D4_1 * g[j - 1];
    int rr = n - (1 << j);
    float wv = rr >= 0 ? wgt : 0.f;
    rr = rr >= 0 ? rr : 0;
    bf16x8_t fv = *(const bf16x8_t*)(frow + (size_t)rr * 64 + c * 8);
#pragma unroll
    for (int q = 0; q < 8; q++) acc[q] += wv * (float)fv[q];
  }
#pragma unroll
  for (int j = 0; j < 10; j++) {       // offsets 3*2^j
    int rr = n - (3 << j);
    float wv = rr >= 0 ? (D4_0 * g[j]) : 0.f;
    rr = rr >= 0 ? rr : 0;
    bf16x8_t fv = *(const bf16x8_t*)(frow + (size_t)rr * 64 + c * 8);
#pragma unroll
    for (int q = 0; q < 8; q++) acc[q] += wv * (float)fv[q];
  }
  bf16x8_t o;
#pragma unroll
  for (int q = 0; q < 8; q++) o[q] = (bf16_t)acc[q];
  *(bf16x8_t*)(facc + ((size_t)bh * 2048 + n) * 64 + c * 8) = o;
}

// ---------------- head coupling softmax mix + gate + bf16 cast ----------------
__global__ __launch_bounds__(1024) void couple_gate_k(const bf16_t* __restrict__ facc,
                                                      const float* __restrict__ fcoup,
                                                      const bf16_t* __restrict__ gate,
                                                      bf16_t* __restrict__ gmat) {
  __shared__ float sacc[1024];
  __shared__ float sc[256];
  __shared__ float scn[256];
  const int tid = threadIdx.x;
  const int bn = blockIdx.x;  // b*2048 + n
  const int b = bn >> 11, n = bn & 2047;
  if (tid < 256) sc[tid] = fcoup[tid];
  const int i = tid >> 6, hd = tid & 63;
  sacc[tid] = (float)facc[(((size_t)(b * 16 + i)) * 2048 + n) * 64 + hd];
  __syncthreads();
  if (tid < 16) {
    float row[16];
    float mx = -1e30f;
#pragma unroll
    for (int j = 0; j < 16; j++) { row[j] = sc[tid * 16 + j]; mx = fmaxf(mx, row[j]); }
    float se = 0.f;
#pragma unroll
    for (int j = 0; j < 16; j++) { row[j] = __expf(row[j] - mx); se += row[j]; }
    float inv = 1.f / se;
#pragma unroll
    for (int j = 0; j < 16; j++) scn[tid * 16 + j] = row[j] * inv;
  }
  __syncthreads();
  float s = 0.f;
#pragma unroll
  for (int j = 0; j < 16; j++) s += scn[i * 16 + j] * sacc[j * 64 + hd];
  const float gt = (float)gate[(size_t)bn * 1024 + tid];
  gmat[(size_t)bn * 1024 + tid] = (bf16_t)(s * gt);
}

// ---------------- launch ----------------
extern "C" void kernel_launch(void* const* d_in, const int* in_sizes, int n_in,
                              void* d_out, int out_size, void* d_ws, size_t ws_size,
                              hipStream_t stream) {
  (void)in_sizes; (void)n_in; (void)out_size; (void)ws_size;
  const float* x = (const float*)d_in[0];
  const float* Wqkv = (const float*)d_in[1];
  const float* bqkv = (const float*)d_in[2];
  const float* Wo = (const float*)d_in[3];
  const float* bo = (const float*)d_in[4];
  const float* Wg = (const float*)d_in[5];
  const float* bg = (const float*)d_in[6];
  const float* scale_gain = (const float*)d_in[7];
  const float* Wqs = (const float*)d_in[8];
  const float* fcoup = (const float*)d_in[9];

  char* ws = (char*)d_ws;
  size_t off = 0;
  auto alloc = [&](size_t bytes) {
    void* p = ws + off;
    off += (bytes + 255) & ~(size_t)255;
    return p;
  };
  bf16_t* xb = (bf16_t*)alloc(8192ull * 1024 * 2);      // 16 MB
  bf16_t* Wab = (bf16_t*)alloc(4096ull * 1024 * 2);     // 8 MB (Wqkv rows then Wg rows)
  bf16_t* Wob = (bf16_t*)alloc(1024ull * 1024 * 2);     // 2 MB
  float* biasA = (float*)alloc(4096ull * 4);
  bf16_t* qkvb = (bf16_t*)alloc(8192ull * 3072 * 2);    // 48 MB
  bf16_t* gateb = (bf16_t*)alloc(8192ull * 1024 * 2);   // 16 MB
  bf16_t* fieldb = (bf16_t*)alloc(8388608ull * 2);      // 16 MB
  float* gains = (float*)alloc(8192ull * 16 * SS * 4);  // 5.8 MB
  bf16_t* facc = (bf16_t*)alloc(8388608ull * 2);        // 16 MB
  bf16_t* gmat = (bf16_t*)alloc(8192ull * 1024 * 2);    // 16 MB

  // bias concat for fused GEMM-A
  hipMemcpyAsync(biasA, bqkv, 3072 * 4, hipMemcpyDeviceToDevice, stream);
  hipMemcpyAsync(biasA + 3072, bg, 1024 * 4, hipMemcpyDeviceToDevice, stream);

  // conversions
  cvt_k<<<8192, 256, 0, stream>>>(x, xb, 8192 * 1024 / 4);
  cvt_k<<<3072, 256, 0, stream>>>(Wqkv, Wab, 3072 * 1024 / 4);
  cvt_k<<<1024, 256, 0, stream>>>(Wg, Wab + 3072ull * 1024, 1024 * 1024 / 4);
  cvt_k<<<1024, 256, 0, stream>>>(Wo, Wob, 1024 * 1024 / 4);

  // GEMM-A: qkv + gate fused (M=8192, N=4096, K=1024), bf16 outputs
  gemm_nt<0><<<64 * 32, 256, 0, stream>>>(xb, Wab, biasA, qkvb, gateb, 8192, 4096, 1024);

  // field + gains (MFMA-based, one wave per bn)
  field_gains_k<<<2048, 256, 0, stream>>>(qkvb, scale_gain, Wqs, fieldb, gains);

  // multiscale conv (XCD-swizzled: blk low 6 bits = bh)
  conv_k<<<4096, 256, 0, stream>>>(fieldb, gains, facc);

  // coupling + gate + bf16 cast
  couple_gate_k<<<8192, 1024, 0, stream>>>(facc, fcoup, gateb, gmat);

  // GEMM-B: output (M=8192, N=1024, K=1024), fp32 out
  gemm_nt<1><<<64 * 8, 256, 0, stream>>>(gmat, Wob, bo, (void*)d_out, nullptr, 8192, 1024, 1024);
}

// Round 5
// 283.322 us; speedup vs baseline: 1.6274x; 1.0254x over previous
//
#include <hip/hip_runtime.h>
#include <hip/hip_bf16.h>
#include <stdint.h>
#include <math.h>

// Problem constants
#define BB 4
#define NN 2048
#define DD 1024
#define HH 16
#define HDD 64
#define SS 11

#define D4_0 0.4829629131445341f
#define D4_1 0.8365163037378079f
#define D4_2 0.2241438680420134f
#define D4_3 (-0.1294095225512604f)

typedef __bf16 bf16_t;
typedef __bf16 bf16x4_t __attribute__((ext_vector_type(4)));
typedef __bf16 bf16x8_t __attribute__((ext_vector_type(8)));
typedef float f32x4_t __attribute__((ext_vector_type(4)));

// ---------------- fused f32 -> bf16 conversion for all 4 tensors ----------------
// ranges (in float4 units): x 2097152 | Wqkv 786432 | Wg 262144 | Wo 262144
__global__ __launch_bounds__(256) void cvt_all_k(const float* __restrict__ s0,
                                                 const float* __restrict__ s1,
                                                 const float* __restrict__ s2,
                                                 const float* __restrict__ s3,
                                                 bf16_t* __restrict__ d0,
                                                 bf16_t* __restrict__ d1,
                                                 bf16_t* __restrict__ d2,
                                                 bf16_t* __restrict__ d3) {
  const int n0 = 2097152, n1 = 786432, n2 = 262144, n3 = 262144;
  int i = blockIdx.x * 256 + threadIdx.x;
  const float* s;
  bf16_t* d;
  if (i < n0) { s = s0; d = d0; }
  else if (i < n0 + n1) { i -= n0; s = s1; d = d1; }
  else if (i < n0 + n1 + n2) { i -= n0 + n1; s = s2; d = d2; }
  else { i -= n0 + n1 + n2; if (i >= n3) return; s = s3; d = d3; }
  f32x4_t v = ((const f32x4_t*)s)[i];
  bf16x4_t o;
  o[0] = (bf16_t)v[0]; o[1] = (bf16_t)v[1]; o[2] = (bf16_t)v[2]; o[3] = (bf16_t)v[3];
  ((bf16x4_t*)d)[i] = o;
}

// ---------------- async global->LDS helper ----------------
__device__ __forceinline__ void gload16(const void* g, void* l) {
  __builtin_amdgcn_global_load_lds((__attribute__((address_space(1))) void*)(void*)g,
                                   (__attribute__((address_space(3))) void*)l,
                                   16, 0, 0);
}

// ---------------- NT bf16 GEMM: C[M,N] = A[M,K] * Bw[N,K]^T + bias ----------------
// XCD swizzle: j = blk % (8*ntiles), g = blk/(8*ntiles); mtile = g*8+(j&7), ntile = j>>3.
// -> the 8 blocks of one round-robin XCD round share ntile (B-panel L3-broadcast);
//    each XCD keeps one 256KB A-panel L2-resident across all ntiles.
// MODE 0: N=4096; cols <3072 -> out0 = qkv bf16 (ld 3072), bias=bias0; cols >=3072 ->
//         out1 = sigmoid bf16 (ld 1024), bias=bias1
// MODE 1: out0[M,N] = fp32 val + bias0 (ld = Nn)
template <int MODE>
__global__ __launch_bounds__(256) void gemm_nt(const bf16_t* __restrict__ A,
                                               const bf16_t* __restrict__ Bw,
                                               const float* __restrict__ bias0,
                                               const float* __restrict__ bias1,
                                               void* __restrict__ out0v,
                                               void* __restrict__ out1v,
                                               int M, int Nn, int K) {
  __shared__ bf16_t As[128 * 64];
  __shared__ bf16_t Bs[128 * 64];

  const int tid = threadIdx.x;
  const int ntiles = Nn >> 7;
  const int grp = ntiles << 3;
  const int g = blockIdx.x / grp;
  const int j = blockIdx.x % grp;
  const int mtile = (g << 3) | (j & 7);
  const int ntile = j >> 3;
  const int row0 = mtile << 7;
  const int col0 = ntile << 7;
  const int w = tid >> 6, lane = tid & 63;
  const int wm = w >> 1, wn = w & 1;
  const int m16 = lane & 15, quad = lane >> 4;

  f32x4_t acc[4][4];
#pragma unroll
  for (int i = 0; i < 4; i++)
#pragma unroll
    for (int jj = 0; jj < 4; jj++) acc[i][jj] = (f32x4_t){0.f, 0.f, 0.f, 0.f};

  for (int kb = 0; kb < K; kb += 64) {
    __syncthreads();  // previous tile's reads done before overwrite
#pragma unroll
    for (int r = 0; r < 4; ++r) {
      int c = r * 256 + tid;       // chunk index (16B units)
      int row = c >> 3, kc = c & 7;
      int swz = kc ^ (row & 7);    // XOR swizzle: LDS chunk kc holds global chunk swz
      const bf16_t* gpA = A + (size_t)(row0 + row) * K + kb + swz * 8;
      const bf16_t* gpB = Bw + (size_t)(col0 + row) * K + kb + swz * 8;
      // wave-uniform LDS base; HW adds lane*16
      bf16_t* lpA = As + (size_t)(r * 256 + (tid & 192)) * 8;
      bf16_t* lpB = Bs + (size_t)(r * 256 + (tid & 192)) * 8;
      gload16(gpA, lpA);
      gload16(gpB, lpB);
    }
    __syncthreads();  // drains vmcnt -> LDS data visible

#pragma unroll
    for (int kk = 0; kk < 2; ++kk) {
      bf16x8_t af[4], bfr[4];
      const int kc = (kk << 2) + quad;
#pragma unroll
      for (int i = 0; i < 4; i++) {
        int arow = (wm << 6) + (i << 4) + m16;
        af[i] = *(const bf16x8_t*)(As + arow * 64 + ((kc ^ (arow & 7)) << 3));
        int brow = (wn << 6) + (i << 4) + m16;
        bfr[i] = *(const bf16x8_t*)(Bs + brow * 64 + ((kc ^ (brow & 7)) << 3));
      }
#pragma unroll
      for (int i = 0; i < 4; i++)
#pragma unroll
        for (int jj = 0; jj < 4; jj++)
          acc[i][jj] = __builtin_amdgcn_mfma_f32_16x16x32_bf16(af[i], bfr[jj], acc[i][jj], 0, 0, 0);
    }
  }

  // epilogue: C[row = quad*4+r][col = lane&15]
#pragma unroll
  for (int i = 0; i < 4; i++) {
#pragma unroll
    for (int jj = 0; jj < 4; jj++) {
      const int grow0 = row0 + (wm << 6) + (i << 4) + (quad << 2);
      const int gcol = col0 + (wn << 6) + (jj << 4) + m16;
      const float bval = (MODE == 0)
                             ? (gcol < 3072 ? bias0[gcol] : bias1[gcol - 3072])
                             : bias0[gcol];
#pragma unroll
      for (int r = 0; r < 4; r++) {
        float val = acc[i][jj][r] + bval;
        if (MODE == 0) {
          if (gcol < 3072)
            ((bf16_t*)out0v)[(size_t)(grow0 + r) * 3072 + gcol] = (bf16_t)val;
          else
            ((bf16_t*)out1v)[(size_t)(grow0 + r) * 1024 + (gcol - 3072)] =
                (bf16_t)(1.f / (1.f + __expf(-val)));
        } else {
          ((float*)out0v)[(size_t)(grow0 + r) * Nn + gcol] = val;
        }
      }
    }
  }
}

// ---------------- field + gains via MFMA: one wave per bn (16 heads) ----------------
__global__ __launch_bounds__(256) void field_gains_k(const bf16_t* __restrict__ qkvb,
                                                     const float* __restrict__ scale_gain,
                                                     const float* __restrict__ Wqs,
                                                     bf16_t* __restrict__ fieldb,
                                                     float* __restrict__ gains) {
  __shared__ float skmag[4 * 16];
  const int tid = threadIdx.x;
  const int w = tid >> 6, lane = tid & 63;
  const int bn = blockIdx.x * 4 + w;  // 0..8191
  const int b = bn >> 11, n_pos = bn & 2047;
  const int m16 = lane & 15, quad = lane >> 4;
  const bf16_t* qp = qkvb + (size_t)bn * 3072;

  // A-fragments: q rows (head = m16), k rows
  bf16x8_t aq[2], ak[2], bw[2];
#pragma unroll
  for (int it = 0; it < 2; it++) {
    const int koff = it * 32 + quad * 8;
    aq[it] = *(const bf16x8_t*)(qp + m16 * 64 + koff);
    ak[it] = *(const bf16x8_t*)(qp + 1024 + m16 * 64 + koff);
    bf16x8_t bwv;
    if (m16 < SS) {
      const float* wp = Wqs + m16 * 64 + koff;
#pragma unroll
      for (int j = 0; j < 8; j++) bwv[j] = (bf16_t)wp[j];
    } else {
#pragma unroll
      for (int j = 0; j < 8; j++) bwv[j] = (bf16_t)0.f;
    }
    bw[it] = bwv;
  }

  f32x4_t acc_l = (f32x4_t){0.f, 0.f, 0.f, 0.f};
  f32x4_t acc_k = (f32x4_t){0.f, 0.f, 0.f, 0.f};
#pragma unroll
  for (int it = 0; it < 2; it++) {
    acc_l = __builtin_amdgcn_mfma_f32_16x16x32_bf16(aq[it], bw[it], acc_l, 0, 0, 0);
    acc_k = __builtin_amdgcn_mfma_f32_16x16x32_bf16(ak[it], ak[it], acc_k, 0, 0, 0);
  }

  // ksq diag extraction: D[m][n], m=quad*4+r, n=m16; diag where m16==m
#pragma unroll
  for (int r = 0; r < 4; r++) {
    if (m16 == quad * 4 + r) skmag[w * 16 + m16] = sqrtf(fmaxf(acc_k[r], 0.f));
  }

  // softmax over s (cols n=m16, valid n<11) for each head row m=quad*4+r
#pragma unroll
  for (int r = 0; r < 4; r++) {
    const int m = quad * 4 + r;
    float lg = (m16 < SS) ? (acc_l[r] + scale_gain[m16 * 16 + m]) : -1e30f;
    float mx = lg;
#pragma unroll
    for (int sh = 1; sh < 16; sh <<= 1) mx = fmaxf(mx, __shfl_xor(mx, sh, 64));
    float e = (m16 < SS) ? __expf(lg - mx) : 0.f;
    float se = e;
#pragma unroll
    for (int sh = 1; sh < 16; sh <<= 1) se += __shfl_xor(se, sh, 64);
    if (m16 < SS)
      gains[((size_t)(b * 16 + m) * 2048 + n_pos) * SS + m16] = e / se;
  }

  __syncthreads();

  // field[bh][n][hd] = v[h][hd] * kmag[h], bf16 out, lane = hd
#pragma unroll
  for (int h = 0; h < 16; h++) {
    const float km = skmag[w * 16 + h];
    const float v = (float)qp[2048 + h * 64 + lane];
    fieldb[((size_t)(b * 16 + h) * 2048 + n_pos) * 64 + lane] = (bf16_t)(v * km);
  }
}

// ---------------- multiscale causal D4 conv, offset-collapsed ----------------
// One wave: 8 n-positions x 64 hd (lane = nsub*8 + c, bf16x8 per lane).
// Block: 4 waves = 32 n. blockIdx low 6 bits = bh -> all tiles of a bh on XCD bh%8.
__global__ __launch_bounds__(256) void conv_k(const bf16_t* __restrict__ field,
                                              const float* __restrict__ gains,
                                              bf16_t* __restrict__ facc) {
  __shared__ float sg[32 * SS];
  const int tid = threadIdx.x;
  const int blk = blockIdx.x;
  const int bh = blk & 63;
  const int ntile = blk >> 6;          // 0..63
  const int n0 = ntile * 32;

  // 352 floats with 256 threads: strided fill
  for (int i = tid; i < 32 * SS; i += 256)
    sg[i] = gains[((size_t)bh * 2048 + n0) * SS + i];
  __syncthreads();

  const int w = tid >> 6, lane = tid & 63;
  const int nsub = lane >> 3, c = lane & 7;
  const int ln = w * 8 + nsub;         // 0..31
  const int n = n0 + ln;
  const bf16_t* frow = field + (size_t)bh * 2048 * 64;

  float g[SS];
#pragma unroll
  for (int s = 0; s < SS; s++) g[s] = sg[ln * SS + s];

  float acc[8];
  {
    bf16x8_t f0 = *(const bf16x8_t*)(frow + (size_t)n * 64 + c * 8);
#pragma unroll
    for (int q = 0; q < 8; q++) acc[q] = D4_3 * (float)f0[q];  // offset 0: sum_s g_s = 1
  }
#pragma unroll
  for (int j = 0; j < 11; j++) {       // offsets 2^j
    float wgt = D4_2 * g[j];
    if (j >= 1) wgt += D4_1 * g[j - 1];
    int rr = n - (1 << j);
    float wv = rr >= 0 ? wgt : 0.f;
    rr = rr >= 0 ? rr : 0;
    bf16x8_t fv = *(const bf16x8_t*)(frow + (size_t)rr * 64 + c * 8);
#pragma unroll
    for (int q = 0; q < 8; q++) acc[q] += wv * (float)fv[q];
  }
#pragma unroll
  for (int j = 0; j < 10; j++) {       // offsets 3*2^j
    int rr = n - (3 << j);
    float wv = rr >= 0 ? (D4_0 * g[j]) : 0.f;
    rr = rr >= 0 ? rr : 0;
    bf16x8_t fv = *(const bf16x8_t*)(frow + (size_t)rr * 64 + c * 8);
#pragma unroll
    for (int q = 0; q < 8; q++) acc[q] += wv * (float)fv[q];
  }
  bf16x8_t o;
#pragma unroll
  for (int q = 0; q < 8; q++) o[q] = (bf16_t)acc[q];
  *(bf16x8_t*)(facc + ((size_t)bh * 2048 + n) * 64 + c * 8) = o;
}

// ---------------- head coupling softmax mix + gate + bf16 cast ----------------
__global__ __launch_bounds__(1024) void couple_gate_k(const bf16_t* __restrict__ facc,
                                                      const float* __restrict__ fcoup,
                                                      const bf16_t* __restrict__ gate,
                                                      bf16_t* __restrict__ gmat) {
  __shared__ float sacc[1024];
  __shared__ float sc[256];
  __shared__ float scn[256];
  const int tid = threadIdx.x;
  const int bn = blockIdx.x;  // b*2048 + n
  const int b = bn >> 11, n = bn & 2047;
  if (tid < 256) sc[tid] = fcoup[tid];
  const int i = tid >> 6, hd = tid & 63;
  sacc[tid] = (float)facc[(((size_t)(b * 16 + i)) * 2048 + n) * 64 + hd];
  __syncthreads();
  if (tid < 16) {
    float row[16];
    float mx = -1e30f;
#pragma unroll
    for (int j = 0; j < 16; j++) { row[j] = sc[tid * 16 + j]; mx = fmaxf(mx, row[j]); }
    float se = 0.f;
#pragma unroll
    for (int j = 0; j < 16; j++) { row[j] = __expf(row[j] - mx); se += row[j]; }
    float inv = 1.f / se;
#pragma unroll
    for (int j = 0; j < 16; j++) scn[tid * 16 + j] = row[j] * inv;
  }
  __syncthreads();
  float s = 0.f;
#pragma unroll
  for (int j = 0; j < 16; j++) s += scn[i * 16 + j] * sacc[j * 64 + hd];
  const float gt = (float)gate[(size_t)bn * 1024 + tid];
  gmat[(size_t)bn * 1024 + tid] = (bf16_t)(s * gt);
}

// ---------------- launch ----------------
extern "C" void kernel_launch(void* const* d_in, const int* in_sizes, int n_in,
                              void* d_out, int out_size, void* d_ws, size_t ws_size,
                              hipStream_t stream) {
  (void)in_sizes; (void)n_in; (void)out_size; (void)ws_size;
  const float* x = (const float*)d_in[0];
  const float* Wqkv = (const float*)d_in[1];
  const float* bqkv = (const float*)d_in[2];
  const float* Wo = (const float*)d_in[3];
  const float* bo = (const float*)d_in[4];
  const float* Wg = (const float*)d_in[5];
  const float* bg = (const float*)d_in[6];
  const float* scale_gain = (const float*)d_in[7];
  const float* Wqs = (const float*)d_in[8];
  const float* fcoup = (const float*)d_in[9];

  char* ws = (char*)d_ws;
  size_t off = 0;
  auto alloc = [&](size_t bytes) {
    void* p = ws + off;
    off += (bytes + 255) & ~(size_t)255;
    return p;
  };
  bf16_t* xb = (bf16_t*)alloc(8192ull * 1024 * 2);      // 16 MB
  bf16_t* Wab = (bf16_t*)alloc(4096ull * 1024 * 2);     // 8 MB (Wqkv rows then Wg rows)
  bf16_t* Wob = (bf16_t*)alloc(1024ull * 1024 * 2);     // 2 MB
  bf16_t* qkvb = (bf16_t*)alloc(8192ull * 3072 * 2);    // 48 MB
  bf16_t* gateb = (bf16_t*)alloc(8192ull * 1024 * 2);   // 16 MB
  bf16_t* fieldb = (bf16_t*)alloc(8388608ull * 2);      // 16 MB
  float* gains = (float*)alloc(8192ull * 16 * SS * 4);  // 5.8 MB
  bf16_t* facc = (bf16_t*)alloc(8388608ull * 2);        // 16 MB
  bf16_t* gmat = (bf16_t*)alloc(8192ull * 1024 * 2);    // 16 MB

  // fused conversions (x, Wqkv, Wg, Wo)
  cvt_all_k<<<13316, 256, 0, stream>>>(x, Wqkv, Wg, Wo,
                                       xb, Wab, Wab + 3072ull * 1024, Wob);

  // GEMM-A: qkv + gate fused (M=8192, N=4096, K=1024), bf16 outputs
  gemm_nt<0><<<64 * 32, 256, 0, stream>>>(xb, Wab, bqkv, bg, qkvb, gateb, 8192, 4096, 1024);

  // field + gains (MFMA-based, one wave per bn)
  field_gains_k<<<2048, 256, 0, stream>>>(qkvb, scale_gain, Wqs, fieldb, gains);

  // multiscale conv (XCD-swizzled: blk low 6 bits = bh)
  conv_k<<<4096, 256, 0, stream>>>(fieldb, gains, facc);

  // coupling + gate + bf16 cast
  couple_gate_k<<<8192, 1024, 0, stream>>>(facc, fcoup, gateb, gmat);

  // GEMM-B: output (M=8192, N=1024, K=1024), fp32 out
  gemm_nt<1><<<64 * 8, 256, 0, stream>>>(gmat, Wob, bo, nullptr, (void*)d_out, nullptr, 8192, 1024, 1024);
}